// Round 1
// baseline (253.951 us; speedup 1.0000x reference)
//
#include <hip/hip_runtime.h>
#include <hip/hip_bf16.h>

typedef float f32x4 __attribute__((ext_vector_type(4)));
typedef short s16x8 __attribute__((ext_vector_type(8)));
typedef unsigned short u16;

#define N_NODES 8192
#define KNBR 16
#define FEAT 128
#define DIST 128
#define NH 8
#define HD 128
#define HID 128
#define SCALE 0.08838834764831845f   // 1/sqrt(128)

__device__ __forceinline__ float bf2f(u16 h) {
    unsigned v = ((unsigned)h) << 16;
    return __builtin_bit_cast(float, v);
}
__device__ __forceinline__ u16 f2bf(float f) {
    unsigned u = __builtin_bit_cast(unsigned, f);
    u += 0x7fffu + ((u >> 16) & 1u);   // RNE
    return (u16)(u >> 16);
}

// ---------------------------------------------------------------------------
// Kernel 0: convert activations to bf16; transpose+convert all weights so that
// B-fragments (Wt[col][k]) are contiguous 16B reads.
// ---------------------------------------------------------------------------
__global__ void prep_kernel(const float* __restrict__ feat, const float* __restrict__ dist,
                            const float* __restrict__ Wq, const float* __restrict__ Wk,
                            const float* __restrict__ Wv, const float* __restrict__ Wo,
                            const float* __restrict__ W1, const float* __restrict__ W2,
                            const float* __restrict__ W3, const float* __restrict__ W4,
                            u16* __restrict__ featb, u16* __restrict__ distb,
                            u16* __restrict__ Wqkvt, u16* __restrict__ Wot,
                            u16* __restrict__ Wmlpt) {
    int gid = blockIdx.x * 256 + threadIdx.x;       // grid covers exactly 8192*128
    featb[gid] = f2bf(feat[gid]);
    distb[gid] = f2bf(dist[gid]);
    if (gid < 3072 * 128) {                         // Wqkvt[col][k], col: q|k|v
        int col = gid >> 7, k = gid & 127;
        float v = (col < 1024) ? Wq[k * 1024 + col]
                : (col < 2048) ? Wk[k * 1024 + (col - 1024)]
                               : Wv[k * 1024 + (col - 2048)];
        Wqkvt[gid] = f2bf(v);
    }
    if (gid < 128 * 1024) {                         // Wot[col][k], k=0..1023
        int col = gid >> 10, k = gid & 1023;
        Wot[gid] = f2bf(Wo[k * 128 + col]);
    }
    if (gid < 4 * 128 * 128) {                      // Wmlpt[layer][col][k]
        int m = gid >> 14, r = gid & 16383;
        int col = r >> 7, k = r & 127;
        const float* Wm = (m == 0) ? W1 : (m == 1) ? W2 : (m == 2) ? W3 : W4;
        Wmlpt[gid] = f2bf(Wm[k * 128 + col]);
    }
}

// ---------------------------------------------------------------------------
// Kernel 1: fused Q/K/V projection GEMM.  M=8192, K=128, N=3072 (q|k|v).
// BM=64 (4 waves x 16 rows), BN=64. Fragments loaded directly from global
// (bf16, 16B per lane) — everything is L1/L2-hot.  Output: qkvb[row][3072].
// ---------------------------------------------------------------------------
__global__ __launch_bounds__(256) void qkv_gemm(const u16* __restrict__ featb,
                                                const u16* __restrict__ distb,
                                                const u16* __restrict__ Wqkvt,
                                                const float* __restrict__ bq,
                                                const float* __restrict__ bk,
                                                const float* __restrict__ bv,
                                                u16* __restrict__ qkvb) {
    const int rt = blockIdx.x, ct = blockIdx.y;
    const int w = threadIdx.x >> 6, l = threadIdx.x & 63;
    const int rbase = rt * 64 + w * 16;
    const int cbase = ct * 64;
    const u16* A = (cbase < 1024) ? distb : featb;   // q from distance feats

    const u16* arow = A + (size_t)(rbase + (l & 15)) * 128 + ((l >> 4) * 8);

    f32x4 acc[4];
#pragma unroll
    for (int i = 0; i < 4; i++) acc[i] = (f32x4){0.f, 0.f, 0.f, 0.f};

#pragma unroll
    for (int kk = 0; kk < 4; kk++) {
        s16x8 af = *(const s16x8*)(arow + kk * 32);
#pragma unroll
        for (int nf = 0; nf < 4; nf++) {
            const u16* bp = Wqkvt + (size_t)(cbase + nf * 16 + (l & 15)) * 128
                          + kk * 32 + ((l >> 4) * 8);
            s16x8 bf = *(const s16x8*)bp;
            acc[nf] = __builtin_amdgcn_mfma_f32_16x16x32_bf16(af, bf, acc[nf], 0, 0, 0);
        }
    }
#pragma unroll
    for (int nf = 0; nf < 4; nf++) {
        const int gcol = cbase + nf * 16 + (l & 15);
        const float bias = (gcol < 1024) ? bq[gcol]
                         : (gcol < 2048) ? bk[gcol - 1024] : bv[gcol - 2048];
#pragma unroll
        for (int r = 0; r < 4; r++) {
            const int grow = rbase + (l >> 4) * 4 + r;
            qkvb[(size_t)grow * 3072 + gcol] = f2bf(acc[nf][r] + bias);
        }
    }
}

// ---------------------------------------------------------------------------
// Kernel 2: gather attention. One wave per node. lane = (head h=l>>3, lh=l&7),
// each lane owns 16 d-values of its head. Neighbour indices broadcast by shfl.
// Softmax over 16 neighbours held fully in-lane.
// ---------------------------------------------------------------------------
__global__ __launch_bounds__(256) void attn_kernel(const u16* __restrict__ qkvb,
                                                   const int* __restrict__ structure,
                                                   u16* __restrict__ attb) {
    const int wv = threadIdx.x >> 6, l = threadIdx.x & 63;
    const int n = blockIdx.x * 4 + wv;
    const int h = l >> 3, lh = l & 7;
    const size_t laneoff = h * 128 + lh * 16;

    const u16* qrow = qkvb + (size_t)n * 3072 + laneoff;
    float qf[16];
    {
        s16x8 q0 = *(const s16x8*)qrow;
        s16x8 q1 = *(const s16x8*)(qrow + 8);
#pragma unroll
        for (int t = 0; t < 8; t++) { qf[t] = bf2f((u16)q0[t]); qf[8 + t] = bf2f((u16)q1[t]); }
    }

    int myidx = structure[n * KNBR + (l & 15)];

    float logit[16];
#pragma unroll
    for (int j = 0; j < 16; j++) {
        int idx = __shfl(myidx, j);
        const u16* krow = qkvb + (size_t)idx * 3072 + 1024 + laneoff;
        s16x8 k0 = *(const s16x8*)krow;
        s16x8 k1 = *(const s16x8*)(krow + 8);
        float s = 0.f;
#pragma unroll
        for (int t = 0; t < 8; t++) {
            s += qf[t] * bf2f((u16)k0[t]);
            s += qf[8 + t] * bf2f((u16)k1[t]);
        }
        s += __shfl_xor(s, 1);
        s += __shfl_xor(s, 2);
        s += __shfl_xor(s, 4);
        logit[j] = s * SCALE;
    }

    float m = logit[0];
#pragma unroll
    for (int j = 1; j < 16; j++) m = fmaxf(m, logit[j]);
    float sum = 0.f;
#pragma unroll
    for (int j = 0; j < 16; j++) { logit[j] = __expf(logit[j] - m); sum += logit[j]; }
    const float inv = 1.f / sum;

    float acc[16];
#pragma unroll
    for (int t = 0; t < 16; t++) acc[t] = 0.f;
#pragma unroll
    for (int j = 0; j < 16; j++) {
        int idx = __shfl(myidx, j);
        const u16* vrow = qkvb + (size_t)idx * 3072 + 2048 + laneoff;
        s16x8 v0 = *(const s16x8*)vrow;
        s16x8 v1 = *(const s16x8*)(vrow + 8);
        const float p = logit[j] * inv;
#pragma unroll
        for (int t = 0; t < 8; t++) {
            acc[t]     += p * bf2f((u16)v0[t]);
            acc[8 + t] += p * bf2f((u16)v1[t]);
        }
    }

    s16x8 o0, o1;
#pragma unroll
    for (int t = 0; t < 8; t++) { o0[t] = (short)f2bf(acc[t]); o1[t] = (short)f2bf(acc[8 + t]); }
    u16* orow = attb + (size_t)n * 1024 + laneoff;
    *(s16x8*)orow = o0;
    *(s16x8*)(orow + 8) = o1;
}

// ---------------------------------------------------------------------------
// Kernel 3: out = dist + att@Wo + bo ; then the full 4-layer MLP in-block;
// final = out + mlp.  BM=32 (2 waves x 16 rows), BN=128 (full width).
// No cross-wave data sharing -> zero barriers; LDS used only for the
// per-wave C-layout -> A-layout transpose between layers (double-buffered).
// ---------------------------------------------------------------------------
__global__ __launch_bounds__(128) void out_mlp(const u16* __restrict__ attb,
                                               const u16* __restrict__ Wot,
                                               const u16* __restrict__ Wmlpt,
                                               const float* __restrict__ dist,
                                               const float* __restrict__ bo,
                                               const float* __restrict__ b1,
                                               const float* __restrict__ b2,
                                               const float* __restrict__ b3,
                                               const float* __restrict__ b4,
                                               float* __restrict__ out) {
    __shared__ __attribute__((aligned(16))) u16 act[2][2][16][136]; // [wave][buf][row][col], padded
    const int w = threadIdx.x >> 6, l = threadIdx.x & 63;
    const int rbase = blockIdx.x * 32 + w * 16;

    // ---- phase A: att @ Wo  (K=1024) ----
    f32x4 acc[8];
#pragma unroll
    for (int i = 0; i < 8; i++) acc[i] = (f32x4){0.f, 0.f, 0.f, 0.f};

    const u16* ap = attb + (size_t)(rbase + (l & 15)) * 1024 + ((l >> 4) * 8);
#pragma unroll 4
    for (int kk = 0; kk < 32; kk++) {
        s16x8 af = *(const s16x8*)(ap + kk * 32);
#pragma unroll
        for (int nf = 0; nf < 8; nf++) {
            const u16* bp = Wot + (size_t)(nf * 16 + (l & 15)) * 1024 + kk * 32 + ((l >> 4) * 8);
            s16x8 bf = *(const s16x8*)bp;
            acc[nf] = __builtin_amdgcn_mfma_f32_16x16x32_bf16(af, bf, acc[nf], 0, 0, 0);
        }
    }

    // out = acc + bo + dist; keep f32 copy in regs for the final residual,
    // bf16 copy in LDS as next GEMM's A operand.
    float outsave[8][4];
#pragma unroll
    for (int nf = 0; nf < 8; nf++) {
        const int gcol = nf * 16 + (l & 15);
        const float bv = bo[gcol];
#pragma unroll
        for (int r = 0; r < 4; r++) {
            const int rl = (l >> 4) * 4 + r;
            float v = acc[nf][r] + bv + dist[(size_t)(rbase + rl) * 128 + gcol];
            outsave[nf][r] = v;
            act[w][0][rl][gcol] = f2bf(v);
        }
    }

    // ---- MLP chain: layer L reads buf L&1, writes buf (L+1)&1 ----
#pragma unroll
    for (int layer = 0; layer < 4; layer++) {
        const int rd = layer & 1, wr = (layer + 1) & 1;
        f32x4 macc[8];
#pragma unroll
        for (int i = 0; i < 8; i++) macc[i] = (f32x4){0.f, 0.f, 0.f, 0.f};
#pragma unroll
        for (int kk = 0; kk < 4; kk++) {
            s16x8 af = *(const s16x8*)&act[w][rd][l & 15][kk * 32 + ((l >> 4) * 8)];
#pragma unroll
            for (int nf = 0; nf < 8; nf++) {
                const u16* bp = Wmlpt + layer * 16384
                              + (size_t)(nf * 16 + (l & 15)) * 128 + kk * 32 + ((l >> 4) * 8);
                s16x8 bf = *(const s16x8*)bp;
                macc[nf] = __builtin_amdgcn_mfma_f32_16x16x32_bf16(af, bf, macc[nf], 0, 0, 0);
            }
        }
        const float* bias = (layer == 0) ? b1 : (layer == 1) ? b2 : (layer == 2) ? b3 : b4;
        if (layer < 3) {
#pragma unroll
            for (int nf = 0; nf < 8; nf++) {
                const int gcol = nf * 16 + (l & 15);
                const float bv = bias[gcol];
#pragma unroll
                for (int r = 0; r < 4; r++) {
                    const int rl = (l >> 4) * 4 + r;
                    float v = fmaxf(macc[nf][r] + bv, 0.f);
                    act[w][wr][rl][gcol] = f2bf(v);
                }
            }
        } else {
#pragma unroll
            for (int nf = 0; nf < 8; nf++) {
                const int gcol = nf * 16 + (l & 15);
                const float bv = bias[gcol];
#pragma unroll
                for (int r = 0; r < 4; r++) {
                    const int rl = (l >> 4) * 4 + r;
                    out[(size_t)(rbase + rl) * 128 + gcol] = outsave[nf][r] + macc[nf][r] + bv;
                }
            }
        }
    }
}

// ---------------------------------------------------------------------------
extern "C" void kernel_launch(void* const* d_in, const int* in_sizes, int n_in,
                              void* d_out, int out_size, void* d_ws, size_t ws_size,
                              hipStream_t stream) {
    const float* features = (const float*)d_in[0];
    const float* dist     = (const float*)d_in[1];
    const int*   structure= (const int*)d_in[2];
    const float* Wq = (const float*)d_in[3];  const float* bq = (const float*)d_in[4];
    const float* Wk = (const float*)d_in[5];  const float* bk = (const float*)d_in[6];
    const float* Wv = (const float*)d_in[7];  const float* bv = (const float*)d_in[8];
    const float* Wo = (const float*)d_in[9];  const float* bo = (const float*)d_in[10];
    const float* W1 = (const float*)d_in[11]; const float* b1 = (const float*)d_in[12];
    const float* W2 = (const float*)d_in[13]; const float* b2 = (const float*)d_in[14];
    const float* W3 = (const float*)d_in[15]; const float* b3 = (const float*)d_in[16];
    const float* W4 = (const float*)d_in[17]; const float* b4 = (const float*)d_in[18];
    float* out = (float*)d_out;

    u16* wsp   = (u16*)d_ws;
    u16* qkvb  = wsp;                                   // [8192][3072] bf16 (q|k|v)
    u16* attb  = qkvb  + (size_t)8192 * 3072;           // [8192][1024]
    u16* featb = attb  + (size_t)8192 * 1024;           // [8192][128]
    u16* distb = featb + (size_t)8192 * 128;            // [8192][128]
    u16* Wqkvt = distb + (size_t)8192 * 128;            // [3072][128]
    u16* Wot   = Wqkvt + (size_t)3072 * 128;            // [128][1024]
    u16* Wmlpt = Wot   + (size_t)128 * 1024;            // [4][128][128]

    prep_kernel<<<4096, 256, 0, stream>>>(features, dist, Wq, Wk, Wv, Wo, W1, W2, W3, W4,
                                          featb, distb, Wqkvt, Wot, Wmlpt);
    qkv_gemm<<<dim3(128, 48), 256, 0, stream>>>(featb, distb, Wqkvt, bq, bk, bv, qkvb);
    attn_kernel<<<2048, 256, 0, stream>>>(qkvb, structure, attb);
    out_mlp<<<256, 128, 0, stream>>>(attb, Wot, Wmlpt, dist, bo, b1, b2, b3, b4, out);
}

// Round 2
// 228.298 us; speedup vs baseline: 1.1124x; 1.1124x over previous
//
#include <hip/hip_runtime.h>
#include <hip/hip_bf16.h>

typedef float f32x4 __attribute__((ext_vector_type(4)));
typedef short s16x8 __attribute__((ext_vector_type(8)));
typedef unsigned short u16;

#define N_NODES 8192
#define KNBR 16
#define SCALE 0.08838834764831845f   // 1/sqrt(128)

__device__ __forceinline__ float bf2f(u16 h) {
    unsigned v = ((unsigned)h) << 16;
    return __builtin_bit_cast(float, v);
}
__device__ __forceinline__ u16 f2bf(float f) {
    unsigned u = __builtin_bit_cast(unsigned, f);
    u += 0x7fffu + ((u >> 16) & 1u);   // RNE
    return (u16)(u >> 16);
}

// ---------------------------------------------------------------------------
// Kernel 0: activations -> bf16; weights transposed+converted so B-fragments
// (Wt[col][k]) are contiguous 16B reads; fused qkv bias table.
// ---------------------------------------------------------------------------
__global__ void prep_kernel(const float* __restrict__ feat, const float* __restrict__ dist,
                            const float* __restrict__ Wq, const float* __restrict__ Wk,
                            const float* __restrict__ Wv, const float* __restrict__ Wo,
                            const float* __restrict__ W1, const float* __restrict__ W2,
                            const float* __restrict__ W3, const float* __restrict__ W4,
                            const float* __restrict__ bq, const float* __restrict__ bk,
                            const float* __restrict__ bv,
                            u16* __restrict__ featb, u16* __restrict__ distb,
                            u16* __restrict__ Wqkvt, u16* __restrict__ Wot,
                            u16* __restrict__ Wmlpt, float* __restrict__ bqkv) {
    int gid = blockIdx.x * 256 + threadIdx.x;       // grid covers exactly 8192*128
    featb[gid] = f2bf(feat[gid]);
    distb[gid] = f2bf(dist[gid]);
    if (gid < 3072 * 128) {                         // Wqkvt[col][k], col: q|k|v
        int col = gid >> 7, k = gid & 127;
        float v = (col < 1024) ? Wq[k * 1024 + col]
                : (col < 2048) ? Wk[k * 1024 + (col - 1024)]
                               : Wv[k * 1024 + (col - 2048)];
        Wqkvt[gid] = f2bf(v);
    }
    if (gid < 128 * 1024) {                         // Wot[col][k], k=0..1023
        int col = gid >> 10, k = gid & 1023;
        Wot[gid] = f2bf(Wo[k * 128 + col]);
    }
    if (gid < 4 * 128 * 128) {                      // Wmlpt[layer][col][k]
        int m = gid >> 14, r = gid & 16383;
        int col = r >> 7, k = r & 127;
        const float* Wm = (m == 0) ? W1 : (m == 1) ? W2 : (m == 2) ? W3 : W4;
        Wmlpt[gid] = f2bf(Wm[k * 128 + col]);
    }
    if (gid < 3072) {
        bqkv[gid] = (gid < 1024) ? bq[gid] : (gid < 2048) ? bk[gid - 1024] : bv[gid - 2048];
    }
}

// ---------------------------------------------------------------------------
// Kernel 1: fused Q/K/V projection GEMM.  M=8192, K=128, N=3072 (q|k|v).
// BM=64 (4 waves x 16 rows), BN=128.  Output written HEAD-MAJOR:
// qkvh[s][h][n][d], s=0:q 1:k 2:v  (so the attention gather per head touches
// a contiguous 2MB table that fits one XCD's L2).
// ---------------------------------------------------------------------------
__global__ __launch_bounds__(256) void qkv_gemm(const u16* __restrict__ featb,
                                                const u16* __restrict__ distb,
                                                const u16* __restrict__ Wqkvt,
                                                const float* __restrict__ bqkv,
                                                u16* __restrict__ qkvh) {
    const int rt = blockIdx.x, ct = blockIdx.y;
    const int w = threadIdx.x >> 6, l = threadIdx.x & 63;
    const int rbase = rt * 64 + w * 16;
    const int cbase = ct * 128;
    const u16* A = (cbase < 1024) ? distb : featb;   // q from distance feats

    const u16* arow = A + (size_t)(rbase + (l & 15)) * 128 + ((l >> 4) * 8);

    f32x4 acc[8];
#pragma unroll
    for (int i = 0; i < 8; i++) acc[i] = (f32x4){0.f, 0.f, 0.f, 0.f};

#pragma unroll
    for (int kk = 0; kk < 4; kk++) {
        s16x8 af = *(const s16x8*)(arow + kk * 32);
#pragma unroll
        for (int nf = 0; nf < 8; nf++) {
            const u16* bp = Wqkvt + (size_t)(cbase + nf * 16 + (l & 15)) * 128
                          + kk * 32 + ((l >> 4) * 8);
            s16x8 bf = *(const s16x8*)bp;
            acc[nf] = __builtin_amdgcn_mfma_f32_16x16x32_bf16(af, bf, acc[nf], 0, 0, 0);
        }
    }
#pragma unroll
    for (int nf = 0; nf < 8; nf++) {
        const int gcol = cbase + nf * 16 + (l & 15);
        const float bias = bqkv[gcol];
        const int s = gcol >> 10;            // 0:q 1:k 2:v (uniform per block)
        const int c = gcol & 1023;
        const int head = c >> 7, d = c & 127;
#pragma unroll
        for (int r = 0; r < 4; r++) {
            const int grow = rbase + (l >> 4) * 4 + r;
            qkvh[((size_t)(s * 8 + head) * 8192 + grow) * 128 + d] = f2bf(acc[nf][r] + bias);
        }
    }
}

// ---------------------------------------------------------------------------
// Kernel 2: gather attention, HEAD-PARTITIONED for L2 locality.
// head = blockIdx.x & 7  -> pinned to one XCD (dispatch round-robins XCDs),
// so each XCD's gather working set is K_h + V_h = 4MB = its L2 size.
// Wave handles 8 nodes x 1 head: lane = (node ni = l>>3, d-slice lh = l&7),
// each lane owns 16 d-values. Softmax over 16 neighbours held in-lane.
// ---------------------------------------------------------------------------
__global__ __launch_bounds__(256) void attn_kernel(const u16* __restrict__ qkvh,
                                                   const int* __restrict__ structure,
                                                   u16* __restrict__ attb) {
    const int head = blockIdx.x & 7, chunk = blockIdx.x >> 3;
    const int w = threadIdx.x >> 6, l = threadIdx.x & 63;
    const int ni = l >> 3, lh = l & 7;
    const int n = chunk * 32 + w * 8 + ni;

    const u16* qrow = qkvh + ((size_t)(0 * 8 + head) * 8192 + n) * 128 + lh * 16;
    float qf[16];
    {
        s16x8 q0 = *(const s16x8*)qrow;
        s16x8 q1 = *(const s16x8*)(qrow + 8);
#pragma unroll
        for (int t = 0; t < 8; t++) { qf[t] = bf2f((u16)q0[t]); qf[8 + t] = bf2f((u16)q1[t]); }
    }

    const int2 idx2 = ((const int2*)structure)[n * 8 + lh];   // 2 neighbour idx per lane

    const u16* kbase = qkvh + (size_t)(1 * 8 + head) * 8192 * 128;
    const u16* vbase = qkvh + (size_t)(2 * 8 + head) * 8192 * 128;

    float logit[16];
#pragma unroll
    for (int j = 0; j < 16; j++) {
        int idx = __shfl(j & 1 ? idx2.y : idx2.x, (ni << 3) | (j >> 1));
        const u16* krow = kbase + (size_t)idx * 128 + lh * 16;
        s16x8 k0 = *(const s16x8*)krow;
        s16x8 k1 = *(const s16x8*)(krow + 8);
        float s = 0.f;
#pragma unroll
        for (int t = 0; t < 8; t++) {
            s += qf[t] * bf2f((u16)k0[t]);
            s += qf[8 + t] * bf2f((u16)k1[t]);
        }
        s += __shfl_xor(s, 1);
        s += __shfl_xor(s, 2);
        s += __shfl_xor(s, 4);
        logit[j] = s * SCALE;
    }

    float m = logit[0];
#pragma unroll
    for (int j = 1; j < 16; j++) m = fmaxf(m, logit[j]);
    float sum = 0.f;
#pragma unroll
    for (int j = 0; j < 16; j++) { logit[j] = __expf(logit[j] - m); sum += logit[j]; }
    const float inv = 1.f / sum;

    float acc[16];
#pragma unroll
    for (int t = 0; t < 16; t++) acc[t] = 0.f;
#pragma unroll
    for (int j = 0; j < 16; j++) {
        int idx = __shfl(j & 1 ? idx2.y : idx2.x, (ni << 3) | (j >> 1));
        const u16* vrow = vbase + (size_t)idx * 128 + lh * 16;
        s16x8 v0 = *(const s16x8*)vrow;
        s16x8 v1 = *(const s16x8*)(vrow + 8);
        const float p = logit[j] * inv;
#pragma unroll
        for (int t = 0; t < 8; t++) {
            acc[t]     += p * bf2f((u16)v0[t]);
            acc[8 + t] += p * bf2f((u16)v1[t]);
        }
    }

    s16x8 o0, o1;
#pragma unroll
    for (int t = 0; t < 8; t++) { o0[t] = (short)f2bf(acc[t]); o1[t] = (short)f2bf(acc[8 + t]); }
    u16* orow = attb + (size_t)n * 1024 + head * 128 + lh * 16;   // node-major for Wo GEMM
    *(s16x8*)orow = o0;
    *(s16x8*)(orow + 8) = o1;
}

// ---------------------------------------------------------------------------
// Kernel 3: out = dist + att@Wo + bo ; then the full 4-layer MLP; out + mlp.
// 1 wave per block (BM=16), 512 blocks — latency-bound tail, so maximize
// block count. LDS only for the per-wave C-layout -> A-layout transpose.
// ---------------------------------------------------------------------------
__global__ __launch_bounds__(64) void out_mlp(const u16* __restrict__ attb,
                                              const u16* __restrict__ Wot,
                                              const u16* __restrict__ Wmlpt,
                                              const float* __restrict__ dist,
                                              const float* __restrict__ bo,
                                              const float* __restrict__ b1,
                                              const float* __restrict__ b2,
                                              const float* __restrict__ b3,
                                              const float* __restrict__ b4,
                                              float* __restrict__ out) {
    __shared__ __attribute__((aligned(16))) u16 act[2][16][136];  // [buf][row][col] padded
    const int l = threadIdx.x & 63;
    const int rbase = blockIdx.x * 16;

    // ---- phase A: att @ Wo  (K=1024) ----
    f32x4 acc[8];
#pragma unroll
    for (int i = 0; i < 8; i++) acc[i] = (f32x4){0.f, 0.f, 0.f, 0.f};

    const u16* ap = attb + (size_t)(rbase + (l & 15)) * 1024 + ((l >> 4) * 8);
#pragma unroll 4
    for (int kk = 0; kk < 32; kk++) {
        s16x8 af = *(const s16x8*)(ap + kk * 32);
#pragma unroll
        for (int nf = 0; nf < 8; nf++) {
            const u16* bp = Wot + (size_t)(nf * 16 + (l & 15)) * 1024 + kk * 32 + ((l >> 4) * 8);
            s16x8 bf = *(const s16x8*)bp;
            acc[nf] = __builtin_amdgcn_mfma_f32_16x16x32_bf16(af, bf, acc[nf], 0, 0, 0);
        }
    }

    // out = acc + bo + dist; f32 copy in regs for final residual, bf16 in LDS.
    float outsave[8][4];
#pragma unroll
    for (int nf = 0; nf < 8; nf++) {
        const int gcol = nf * 16 + (l & 15);
        const float bv = bo[gcol];
#pragma unroll
        for (int r = 0; r < 4; r++) {
            const int rl = (l >> 4) * 4 + r;
            float v = acc[nf][r] + bv + dist[(size_t)(rbase + rl) * 128 + gcol];
            outsave[nf][r] = v;
            act[0][rl][gcol] = f2bf(v);
        }
    }

    // ---- MLP chain: layer L reads buf L&1, writes buf (L+1)&1 ----
#pragma unroll
    for (int layer = 0; layer < 4; layer++) {
        const int rd = layer & 1, wr = (layer + 1) & 1;
        f32x4 macc[8];
#pragma unroll
        for (int i = 0; i < 8; i++) macc[i] = (f32x4){0.f, 0.f, 0.f, 0.f};
#pragma unroll
        for (int kk = 0; kk < 4; kk++) {
            s16x8 af = *(const s16x8*)&act[rd][l & 15][kk * 32 + ((l >> 4) * 8)];
#pragma unroll
            for (int nf = 0; nf < 8; nf++) {
                const u16* bp = Wmlpt + layer * 16384
                              + (size_t)(nf * 16 + (l & 15)) * 128 + kk * 32 + ((l >> 4) * 8);
                s16x8 bf = *(const s16x8*)bp;
                macc[nf] = __builtin_amdgcn_mfma_f32_16x16x32_bf16(af, bf, macc[nf], 0, 0, 0);
            }
        }
        const float* bias = (layer == 0) ? b1 : (layer == 1) ? b2 : (layer == 2) ? b3 : b4;
        if (layer < 3) {
#pragma unroll
            for (int nf = 0; nf < 8; nf++) {
                const int gcol = nf * 16 + (l & 15);
                const float bv = bias[gcol];
#pragma unroll
                for (int r = 0; r < 4; r++) {
                    const int rl = (l >> 4) * 4 + r;
                    act[wr][rl][gcol] = f2bf(fmaxf(macc[nf][r] + bv, 0.f));
                }
            }
        } else {
#pragma unroll
            for (int nf = 0; nf < 8; nf++) {
                const int gcol = nf * 16 + (l & 15);
                const float bv = bias[gcol];
#pragma unroll
                for (int r = 0; r < 4; r++) {
                    const int rl = (l >> 4) * 4 + r;
                    out[(size_t)(rbase + rl) * 128 + gcol] = outsave[nf][r] + macc[nf][r] + bv;
                }
            }
        }
    }
}

// ---------------------------------------------------------------------------
extern "C" void kernel_launch(void* const* d_in, const int* in_sizes, int n_in,
                              void* d_out, int out_size, void* d_ws, size_t ws_size,
                              hipStream_t stream) {
    const float* features = (const float*)d_in[0];
    const float* dist     = (const float*)d_in[1];
    const int*   structure= (const int*)d_in[2];
    const float* Wq = (const float*)d_in[3];  const float* bq = (const float*)d_in[4];
    const float* Wk = (const float*)d_in[5];  const float* bk = (const float*)d_in[6];
    const float* Wv = (const float*)d_in[7];  const float* bv = (const float*)d_in[8];
    const float* Wo = (const float*)d_in[9];  const float* bo = (const float*)d_in[10];
    const float* W1 = (const float*)d_in[11]; const float* b1 = (const float*)d_in[12];
    const float* W2 = (const float*)d_in[13]; const float* b2 = (const float*)d_in[14];
    const float* W3 = (const float*)d_in[15]; const float* b3 = (const float*)d_in[16];
    const float* W4 = (const float*)d_in[17]; const float* b4 = (const float*)d_in[18];
    float* out = (float*)d_out;

    u16* wsp   = (u16*)d_ws;
    u16* qkvh  = wsp;                                   // [3][8][8192][128] bf16 head-major
    u16* attb  = qkvh  + (size_t)3 * 8 * 8192 * 128;    // [8192][1024]
    u16* featb = attb  + (size_t)8192 * 1024;           // [8192][128]
    u16* distb = featb + (size_t)8192 * 128;            // [8192][128]
    u16* Wqkvt = distb + (size_t)8192 * 128;            // [3072][128]
    u16* Wot   = Wqkvt + (size_t)3072 * 128;            // [128][1024]
    u16* Wmlpt = Wot   + (size_t)128 * 1024;            // [4][128][128]
    float* bqkv = (float*)(Wmlpt + (size_t)4 * 128 * 128); // [3072]

    prep_kernel<<<4096, 256, 0, stream>>>(features, dist, Wq, Wk, Wv, Wo, W1, W2, W3, W4,
                                          bq, bk, bv, featb, distb, Wqkvt, Wot, Wmlpt, bqkv);
    qkv_gemm<<<dim3(128, 24), 256, 0, stream>>>(featb, distb, Wqkvt, bqkv, qkvh);
    attn_kernel<<<2048, 256, 0, stream>>>(qkvh, structure, attb);
    out_mlp<<<512, 64, 0, stream>>>(attb, Wot, Wmlpt, dist, bo, b1, b2, b3, b4, out);
}

// Round 3
// 189.639 us; speedup vs baseline: 1.3391x; 1.2039x over previous
//
#include <hip/hip_runtime.h>
#include <hip/hip_bf16.h>

typedef float f32x4 __attribute__((ext_vector_type(4)));
typedef short s16x8 __attribute__((ext_vector_type(8)));
typedef unsigned short u16;

#define N_NODES 8192
#define KNBR 16
#define SCALE 0.08838834764831845f   // 1/sqrt(128)

__device__ __forceinline__ float bf2f(u16 h) {
    unsigned v = ((unsigned)h) << 16;
    return __builtin_bit_cast(float, v);
}
__device__ __forceinline__ u16 f2bf(float f) {
    __hip_bfloat16 h = __float2bfloat16(f);   // RNE; compiler emits cvt_pk pairs
    return __builtin_bit_cast(u16, h);
}

// ---------------------------------------------------------------------------
// Kernel 0: activations -> bf16; weights transposed+converted so B-fragments
// (Wt[col][k]) are contiguous 16B reads; fused qkv bias table.
// ---------------------------------------------------------------------------
__global__ void prep_kernel(const float* __restrict__ feat, const float* __restrict__ dist,
                            const float* __restrict__ Wq, const float* __restrict__ Wk,
                            const float* __restrict__ Wv, const float* __restrict__ Wo,
                            const float* __restrict__ W1, const float* __restrict__ W2,
                            const float* __restrict__ W3, const float* __restrict__ W4,
                            const float* __restrict__ bq, const float* __restrict__ bk,
                            const float* __restrict__ bv,
                            u16* __restrict__ featb, u16* __restrict__ distb,
                            u16* __restrict__ Wqkvt, u16* __restrict__ Wot,
                            u16* __restrict__ Wmlpt, float* __restrict__ bqkv) {
    int gid = blockIdx.x * 256 + threadIdx.x;       // grid covers exactly 8192*128
    featb[gid] = f2bf(feat[gid]);
    distb[gid] = f2bf(dist[gid]);
    if (gid < 3072 * 128) {                         // Wqkvt[col][k], col: q|k|v
        int col = gid >> 7, k = gid & 127;
        float v = (col < 1024) ? Wq[k * 1024 + col]
                : (col < 2048) ? Wk[k * 1024 + (col - 1024)]
                               : Wv[k * 1024 + (col - 2048)];
        Wqkvt[gid] = f2bf(v);
    }
    if (gid < 128 * 1024) {                         // Wot[col][k], k=0..1023
        int col = gid >> 10, k = gid & 1023;
        Wot[gid] = f2bf(Wo[k * 128 + col]);
    }
    if (gid < 4 * 128 * 128) {                      // Wmlpt[layer][col][k]
        int m = gid >> 14, r = gid & 16383;
        int col = r >> 7, k = r & 127;
        const float* Wm = (m == 0) ? W1 : (m == 1) ? W2 : (m == 2) ? W3 : W4;
        Wmlpt[gid] = f2bf(Wm[k * 128 + col]);
    }
    if (gid < 3072) {
        bqkv[gid] = (gid < 1024) ? bq[gid] : (gid < 2048) ? bk[gid - 1024] : bv[gid - 2048];
    }
}

// ---------------------------------------------------------------------------
// Kernel 1: fused Q/K/V projection GEMM.  M=8192, K=128, N=3072 (q|k|v).
// Block = 4 waves; each wave owns a 64x128 output tile (block 256x128).
// Per wave: preload 16 A-frags, then 8 x {4 B-loads + 16 MFMA} -> 128 MFMA
// vs 48 loads (was 32:36 -> latency-bound at VGPR=44). acc=128 VGPR, so
// __launch_bounds__(256,2) to cap at 256 VGPR (2 blocks/CU).
// Col-tile 128 = exactly one (s,head) of head-major qkvh[s][h][n][d].
// ---------------------------------------------------------------------------
__global__ __launch_bounds__(256, 2) void qkv_gemm(const u16* __restrict__ featb,
                                                   const u16* __restrict__ distb,
                                                   const u16* __restrict__ Wqkvt,
                                                   const float* __restrict__ bqkv,
                                                   u16* __restrict__ qkvh) {
    const int rt = blockIdx.x, ct = blockIdx.y;      // 32 x 24
    const int w = threadIdx.x >> 6, l = threadIdx.x & 63;
    const int rbase = rt * 256 + w * 64;
    const int cbase = ct * 128;
    const u16* A = (ct < 8) ? distb : featb;         // q from distance feats

    // preload A fragments: mf 0..3 (16-row groups), kk 0..3 (32-k slices)
    s16x8 af[4][4];
#pragma unroll
    for (int mf = 0; mf < 4; mf++) {
        const u16* ar = A + (size_t)(rbase + mf * 16 + (l & 15)) * 128 + ((l >> 4) * 8);
#pragma unroll
        for (int kk = 0; kk < 4; kk++) af[mf][kk] = *(const s16x8*)(ar + kk * 32);
    }

    f32x4 acc[4][8];
#pragma unroll
    for (int mf = 0; mf < 4; mf++)
#pragma unroll
        for (int nf = 0; nf < 8; nf++) acc[mf][nf] = (f32x4){0.f, 0.f, 0.f, 0.f};

#pragma unroll
    for (int nf = 0; nf < 8; nf++) {
        const u16* bp = Wqkvt + (size_t)(cbase + nf * 16 + (l & 15)) * 128 + ((l >> 4) * 8);
        s16x8 b0 = *(const s16x8*)bp;
        s16x8 b1 = *(const s16x8*)(bp + 32);
        s16x8 b2 = *(const s16x8*)(bp + 64);
        s16x8 b3 = *(const s16x8*)(bp + 96);
#pragma unroll
        for (int mf = 0; mf < 4; mf++) {
            acc[mf][nf] = __builtin_amdgcn_mfma_f32_16x16x32_bf16(af[mf][0], b0, acc[mf][nf], 0, 0, 0);
            acc[mf][nf] = __builtin_amdgcn_mfma_f32_16x16x32_bf16(af[mf][1], b1, acc[mf][nf], 0, 0, 0);
            acc[mf][nf] = __builtin_amdgcn_mfma_f32_16x16x32_bf16(af[mf][2], b2, acc[mf][nf], 0, 0, 0);
            acc[mf][nf] = __builtin_amdgcn_mfma_f32_16x16x32_bf16(af[mf][3], b3, acc[mf][nf], 0, 0, 0);
        }
    }

    // epilogue: bias + bf16 store. Output region for this block is the
    // contiguous [256 rows][128 d] slab at qkvh + ct*8192*128.
    float bias[8];
#pragma unroll
    for (int nf = 0; nf < 8; nf++) bias[nf] = bqkv[cbase + nf * 16 + (l & 15)];

    u16* obase = qkvh + ((size_t)ct * 8192 + rbase) * 128 + (l & 15);
#pragma unroll
    for (int mf = 0; mf < 4; mf++) {
#pragma unroll
        for (int nf = 0; nf < 8; nf++) {
#pragma unroll
            for (int r = 0; r < 4; r++) {
                const int row = mf * 16 + (l >> 4) * 4 + r;
                obase[(size_t)row * 128 + nf * 16] = f2bf(acc[mf][nf][r] + bias[nf]);
            }
        }
    }
}

// ---------------------------------------------------------------------------
// Kernel 2: gather attention, HEAD-PARTITIONED for L2 locality.
// head = blockIdx.x & 7  -> pinned to one XCD (dispatch round-robins XCDs),
// so each XCD's gather working set is K_h + V_h = 4MB = its L2 size.
// Wave handles 8 nodes x 1 head: lane = (node ni = l>>3, d-slice lh = l&7),
// each lane owns 16 d-values. Softmax over 16 neighbours held in-lane.
// ---------------------------------------------------------------------------
__global__ __launch_bounds__(256) void attn_kernel(const u16* __restrict__ qkvh,
                                                   const int* __restrict__ structure,
                                                   u16* __restrict__ attb) {
    const int head = blockIdx.x & 7, chunk = blockIdx.x >> 3;
    const int w = threadIdx.x >> 6, l = threadIdx.x & 63;
    const int ni = l >> 3, lh = l & 7;
    const int n = chunk * 32 + w * 8 + ni;

    const u16* qrow = qkvh + ((size_t)(0 * 8 + head) * 8192 + n) * 128 + lh * 16;
    float qf[16];
    {
        s16x8 q0 = *(const s16x8*)qrow;
        s16x8 q1 = *(const s16x8*)(qrow + 8);
#pragma unroll
        for (int t = 0; t < 8; t++) { qf[t] = bf2f((u16)q0[t]); qf[8 + t] = bf2f((u16)q1[t]); }
    }

    const int2 idx2 = ((const int2*)structure)[n * 8 + lh];   // 2 neighbour idx per lane

    const u16* kbase = qkvh + (size_t)(1 * 8 + head) * 8192 * 128;
    const u16* vbase = qkvh + (size_t)(2 * 8 + head) * 8192 * 128;

    float logit[16];
#pragma unroll
    for (int j = 0; j < 16; j++) {
        int idx = __shfl(j & 1 ? idx2.y : idx2.x, (ni << 3) | (j >> 1));
        const u16* krow = kbase + (size_t)idx * 128 + lh * 16;
        s16x8 k0 = *(const s16x8*)krow;
        s16x8 k1 = *(const s16x8*)(krow + 8);
        float s = 0.f;
#pragma unroll
        for (int t = 0; t < 8; t++) {
            s += qf[t] * bf2f((u16)k0[t]);
            s += qf[8 + t] * bf2f((u16)k1[t]);
        }
        s += __shfl_xor(s, 1);
        s += __shfl_xor(s, 2);
        s += __shfl_xor(s, 4);
        logit[j] = s * SCALE;
    }

    float m = logit[0];
#pragma unroll
    for (int j = 1; j < 16; j++) m = fmaxf(m, logit[j]);
    float sum = 0.f;
#pragma unroll
    for (int j = 0; j < 16; j++) { logit[j] = __expf(logit[j] - m); sum += logit[j]; }
    const float inv = 1.f / sum;

    float acc[16];
#pragma unroll
    for (int t = 0; t < 16; t++) acc[t] = 0.f;
#pragma unroll
    for (int j = 0; j < 16; j++) {
        int idx = __shfl(j & 1 ? idx2.y : idx2.x, (ni << 3) | (j >> 1));
        const u16* vrow = vbase + (size_t)idx * 128 + lh * 16;
        s16x8 v0 = *(const s16x8*)vrow;
        s16x8 v1 = *(const s16x8*)(vrow + 8);
        const float p = logit[j] * inv;
#pragma unroll
        for (int t = 0; t < 8; t++) {
            acc[t]     += p * bf2f((u16)v0[t]);
            acc[8 + t] += p * bf2f((u16)v1[t]);
        }
    }

    s16x8 o0, o1;
#pragma unroll
    for (int t = 0; t < 8; t++) { o0[t] = (short)f2bf(acc[t]); o1[t] = (short)f2bf(acc[8 + t]); }
    u16* orow = attb + (size_t)n * 1024 + head * 128 + lh * 16;   // node-major for Wo GEMM
    *(s16x8*)orow = o0;
    *(s16x8*)(orow + 8) = o1;
}

// ---------------------------------------------------------------------------
// Kernel 3: out = dist + att@Wo + bo ; then the full 4-layer MLP; out + mlp.
// Block = 2 waves sharing 16 rows, splitting the 128 columns (64 each):
// halves the per-wave dependent-load chain vs 1-wave blocks and doubles
// waves/CU to 4. Double-buffered LDS activation tile, 1 barrier per layer
// (write-buffer of layer L is the read-buffer of layer L-1, so the single
// end-of-layer barrier orders all cross-wave access).
// ---------------------------------------------------------------------------
__global__ __launch_bounds__(128) void out_mlp(const u16* __restrict__ attb,
                                               const u16* __restrict__ Wot,
                                               const u16* __restrict__ Wmlpt,
                                               const float* __restrict__ dist,
                                               const float* __restrict__ bo,
                                               const float* __restrict__ b1,
                                               const float* __restrict__ b2,
                                               const float* __restrict__ b3,
                                               const float* __restrict__ b4,
                                               float* __restrict__ out) {
    __shared__ __attribute__((aligned(16))) u16 act[2][16][136];  // [buf][row][col] padded
    const int w = threadIdx.x >> 6, l = threadIdx.x & 63;
    const int rbase = blockIdx.x * 16;
    const int cb = w * 64;                       // wave's column half

    // ---- phase A: att @ Wo  (K=1024), wave covers cols [cb, cb+64) ----
    f32x4 acc[4];
#pragma unroll
    for (int i = 0; i < 4; i++) acc[i] = (f32x4){0.f, 0.f, 0.f, 0.f};

    const u16* ap = attb + (size_t)(rbase + (l & 15)) * 1024 + ((l >> 4) * 8);
#pragma unroll 4
    for (int kk = 0; kk < 32; kk++) {
        s16x8 af = *(const s16x8*)(ap + kk * 32);
#pragma unroll
        for (int nf = 0; nf < 4; nf++) {
            const u16* bp = Wot + (size_t)(cb + nf * 16 + (l & 15)) * 1024 + kk * 32 + ((l >> 4) * 8);
            s16x8 bf = *(const s16x8*)bp;
            acc[nf] = __builtin_amdgcn_mfma_f32_16x16x32_bf16(af, bf, acc[nf], 0, 0, 0);
        }
    }

    // out = acc + bo + dist; f32 copy in regs for final residual, bf16 in LDS.
    float outsave[4][4];
#pragma unroll
    for (int nf = 0; nf < 4; nf++) {
        const int gcol = cb + nf * 16 + (l & 15);
        const float bv = bo[gcol];
#pragma unroll
        for (int r = 0; r < 4; r++) {
            const int rl = (l >> 4) * 4 + r;
            float v = acc[nf][r] + bv + dist[(size_t)(rbase + rl) * 128 + gcol];
            outsave[nf][r] = v;
            act[0][rl][gcol] = f2bf(v);
        }
    }
    __syncthreads();

    // ---- MLP chain: layer L reads buf L&1, writes buf (L+1)&1 ----
#pragma unroll
    for (int layer = 0; layer < 4; layer++) {
        const int rd = layer & 1, wr = (layer + 1) & 1;
        f32x4 macc[4];
#pragma unroll
        for (int i = 0; i < 4; i++) macc[i] = (f32x4){0.f, 0.f, 0.f, 0.f};
#pragma unroll
        for (int kk = 0; kk < 4; kk++) {
            s16x8 af = *(const s16x8*)&act[rd][l & 15][kk * 32 + ((l >> 4) * 8)];
#pragma unroll
            for (int nf = 0; nf < 4; nf++) {
                const u16* bp = Wmlpt + layer * 16384
                              + (size_t)(cb + nf * 16 + (l & 15)) * 128 + kk * 32 + ((l >> 4) * 8);
                s16x8 bf = *(const s16x8*)bp;
                macc[nf] = __builtin_amdgcn_mfma_f32_16x16x32_bf16(af, bf, macc[nf], 0, 0, 0);
            }
        }
        const float* bias = (layer == 0) ? b1 : (layer == 1) ? b2 : (layer == 2) ? b3 : b4;
        if (layer < 3) {
#pragma unroll
            for (int nf = 0; nf < 4; nf++) {
                const int gcol = cb + nf * 16 + (l & 15);
                const float bv = bias[gcol];
#pragma unroll
                for (int r = 0; r < 4; r++) {
                    const int rl = (l >> 4) * 4 + r;
                    act[wr][rl][gcol] = f2bf(fmaxf(macc[nf][r] + bv, 0.f));
                }
            }
            __syncthreads();
        } else {
#pragma unroll
            for (int nf = 0; nf < 4; nf++) {
                const int gcol = cb + nf * 16 + (l & 15);
                const float bv = bias[gcol];
#pragma unroll
                for (int r = 0; r < 4; r++) {
                    const int rl = (l >> 4) * 4 + r;
                    out[(size_t)(rbase + rl) * 128 + gcol] = outsave[nf][r] + macc[nf][r] + bv;
                }
            }
        }
    }
}

// ---------------------------------------------------------------------------
extern "C" void kernel_launch(void* const* d_in, const int* in_sizes, int n_in,
                              void* d_out, int out_size, void* d_ws, size_t ws_size,
                              hipStream_t stream) {
    const float* features = (const float*)d_in[0];
    const float* dist     = (const float*)d_in[1];
    const int*   structure= (const int*)d_in[2];
    const float* Wq = (const float*)d_in[3];  const float* bq = (const float*)d_in[4];
    const float* Wk = (const float*)d_in[5];  const float* bk = (const float*)d_in[6];
    const float* Wv = (const float*)d_in[7];  const float* bv = (const float*)d_in[8];
    const float* Wo = (const float*)d_in[9];  const float* bo = (const float*)d_in[10];
    const float* W1 = (const float*)d_in[11]; const float* b1 = (const float*)d_in[12];
    const float* W2 = (const float*)d_in[13]; const float* b2 = (const float*)d_in[14];
    const float* W3 = (const float*)d_in[15]; const float* b3 = (const float*)d_in[16];
    const float* W4 = (const float*)d_in[17]; const float* b4 = (const float*)d_in[18];
    float* out = (float*)d_out;

    u16* wsp   = (u16*)d_ws;
    u16* qkvh  = wsp;                                   // [3][8][8192][128] bf16 head-major
    u16* attb  = qkvh  + (size_t)3 * 8 * 8192 * 128;    // [8192][1024]
    u16* featb = attb  + (size_t)8192 * 1024;           // [8192][128]
    u16* distb = featb + (size_t)8192 * 128;            // [8192][128]
    u16* Wqkvt = distb + (size_t)8192 * 128;            // [3072][128]
    u16* Wot   = Wqkvt + (size_t)3072 * 128;            // [128][1024]
    u16* Wmlpt = Wot   + (size_t)128 * 1024;            // [4][128][128]
    float* bqkv = (float*)(Wmlpt + (size_t)4 * 128 * 128); // [3072]

    prep_kernel<<<4096, 256, 0, stream>>>(features, dist, Wq, Wk, Wv, Wo, W1, W2, W3, W4,
                                          bq, bk, bv, featb, distb, Wqkvt, Wot, Wmlpt, bqkv);
    qkv_gemm<<<dim3(32, 24), 256, 0, stream>>>(featb, distb, Wqkvt, bqkv, qkvh);
    attn_kernel<<<2048, 256, 0, stream>>>(qkvh, structure, attb);
    out_mlp<<<512, 128, 0, stream>>>(attb, Wot, Wmlpt, dist, bo, b1, b2, b3, b4, out);
}

// Round 6
// 189.390 us; speedup vs baseline: 1.3409x; 1.0013x over previous
//
#include <hip/hip_runtime.h>
#include <hip/hip_bf16.h>

typedef float f32x4 __attribute__((ext_vector_type(4)));
typedef short s16x8 __attribute__((ext_vector_type(8)));
typedef _Float16 h8v __attribute__((ext_vector_type(8)));
typedef _Float16 h4v __attribute__((ext_vector_type(4)));
typedef _Float16 h2v __attribute__((ext_vector_type(2)));
typedef unsigned short u16;

#define N_NODES 8192
#define KNBR 16
#define SCALE 0.08838834764831845f   // 1/sqrt(128)

__device__ __forceinline__ float bf2f(u16 h) {
    unsigned v = ((unsigned)h) << 16;
    return __builtin_bit_cast(float, v);
}
__device__ __forceinline__ u16 f2bf(float f) {
    __hip_bfloat16 h = __float2bfloat16(f);   // RNE; compiler emits cvt_pk pairs
    return __builtin_bit_cast(u16, h);
}
__device__ __forceinline__ u16 f2h(float f) {
    _Float16 h = (_Float16)f;                  // RNE f32->f16
    return __builtin_bit_cast(u16, h);
}

// ---------------------------------------------------------------------------
// Kernel 0: activations -> bf16; weights transposed+converted so B-fragments
// (Wt[col][k]) are contiguous 16B reads; fused qkv bias table.
// ---------------------------------------------------------------------------
__global__ void prep_kernel(const float* __restrict__ feat, const float* __restrict__ dist,
                            const float* __restrict__ Wq, const float* __restrict__ Wk,
                            const float* __restrict__ Wv, const float* __restrict__ Wo,
                            const float* __restrict__ W1, const float* __restrict__ W2,
                            const float* __restrict__ W3, const float* __restrict__ W4,
                            const float* __restrict__ bq, const float* __restrict__ bk,
                            const float* __restrict__ bv,
                            u16* __restrict__ featb, u16* __restrict__ distb,
                            u16* __restrict__ Wqkvt, u16* __restrict__ Wot,
                            u16* __restrict__ Wmlpt, float* __restrict__ bqkv) {
    int gid = blockIdx.x * 256 + threadIdx.x;       // grid covers exactly 8192*128
    featb[gid] = f2bf(feat[gid]);
    distb[gid] = f2bf(dist[gid]);
    if (gid < 3072 * 128) {                         // Wqkvt[col][k], col: q|k|v
        int col = gid >> 7, k = gid & 127;
        float v = (col < 1024) ? Wq[k * 1024 + col]
                : (col < 2048) ? Wk[k * 1024 + (col - 1024)]
                               : Wv[k * 1024 + (col - 2048)];
        Wqkvt[gid] = f2bf(v);
    }
    if (gid < 128 * 1024) {                         // Wot[col][k], k=0..1023
        int col = gid >> 10, k = gid & 1023;
        Wot[gid] = f2bf(Wo[k * 128 + col]);
    }
    if (gid < 4 * 128 * 128) {                      // Wmlpt[layer][col][k]
        int m = gid >> 14, r = gid & 16383;
        int col = r >> 7, k = r & 127;
        const float* Wm = (m == 0) ? W1 : (m == 1) ? W2 : (m == 2) ? W3 : W4;
        Wmlpt[gid] = f2bf(Wm[k * 128 + col]);
    }
    if (gid < 3072) {
        bqkv[gid] = (gid < 1024) ? bq[gid] : (gid < 2048) ? bk[gid - 1024] : bv[gid - 2048];
    }
}

// ---------------------------------------------------------------------------
// Kernel 1: fused Q/K/V projection GEMM.  M=8192, K=128, N=3072 (q|k|v).
// Block = 4 waves; each wave owns a 64x128 output tile.  128 MFMA : 48 loads.
// Output is written HEAD-MAJOR as **f16** (qkvh[s][h][n][d]) for the packed-
// f16 attention gather; attb (attn output) stays bf16 for the Wo MFMA.
// ---------------------------------------------------------------------------
__global__ __launch_bounds__(256, 2) void qkv_gemm(const u16* __restrict__ featb,
                                                   const u16* __restrict__ distb,
                                                   const u16* __restrict__ Wqkvt,
                                                   const float* __restrict__ bqkv,
                                                   u16* __restrict__ qkvh) {
    const int rt = blockIdx.x, ct = blockIdx.y;      // 32 x 24
    const int w = threadIdx.x >> 6, l = threadIdx.x & 63;
    const int rbase = rt * 256 + w * 64;
    const int cbase = ct * 128;
    const u16* A = (ct < 8) ? distb : featb;         // q from distance feats

    // preload A fragments: mf 0..3 (16-row groups), kk 0..3 (32-k slices)
    s16x8 af[4][4];
#pragma unroll
    for (int mf = 0; mf < 4; mf++) {
        const u16* ar = A + (size_t)(rbase + mf * 16 + (l & 15)) * 128 + ((l >> 4) * 8);
#pragma unroll
        for (int kk = 0; kk < 4; kk++) af[mf][kk] = *(const s16x8*)(ar + kk * 32);
    }

    f32x4 acc[4][8];
#pragma unroll
    for (int mf = 0; mf < 4; mf++)
#pragma unroll
        for (int nf = 0; nf < 8; nf++) acc[mf][nf] = (f32x4){0.f, 0.f, 0.f, 0.f};

#pragma unroll
    for (int nf = 0; nf < 8; nf++) {
        const u16* bp = Wqkvt + (size_t)(cbase + nf * 16 + (l & 15)) * 128 + ((l >> 4) * 8);
        s16x8 b0 = *(const s16x8*)bp;
        s16x8 b1 = *(const s16x8*)(bp + 32);
        s16x8 b2 = *(const s16x8*)(bp + 64);
        s16x8 b3 = *(const s16x8*)(bp + 96);
#pragma unroll
        for (int mf = 0; mf < 4; mf++) {
            acc[mf][nf] = __builtin_amdgcn_mfma_f32_16x16x32_bf16(af[mf][0], b0, acc[mf][nf], 0, 0, 0);
            acc[mf][nf] = __builtin_amdgcn_mfma_f32_16x16x32_bf16(af[mf][1], b1, acc[mf][nf], 0, 0, 0);
            acc[mf][nf] = __builtin_amdgcn_mfma_f32_16x16x32_bf16(af[mf][2], b2, acc[mf][nf], 0, 0, 0);
            acc[mf][nf] = __builtin_amdgcn_mfma_f32_16x16x32_bf16(af[mf][3], b3, acc[mf][nf], 0, 0, 0);
        }
    }

    float bias[8];
#pragma unroll
    for (int nf = 0; nf < 8; nf++) bias[nf] = bqkv[cbase + nf * 16 + (l & 15)];

    u16* obase = qkvh + ((size_t)ct * 8192 + rbase) * 128 + (l & 15);
#pragma unroll
    for (int mf = 0; mf < 4; mf++) {
#pragma unroll
        for (int nf = 0; nf < 8; nf++) {
#pragma unroll
            for (int r = 0; r < 4; r++) {
                const int row = mf * 16 + (l >> 4) * 4 + r;
                obase[(size_t)row * 128 + nf * 16] = f2h(acc[mf][nf][r] + bias[nf]);
            }
        }
    }
}

// ---------------------------------------------------------------------------
// Kernel 2: gather attention, head-partitioned (head = blockIdx.x & 7 -> one
// XCD; per-XCD K/V working set = 4MB = L2).  Packed-f16 math: QK dot and PV
// accumulate in 2-wide f16 vector ops (v_pk_*).  Loads batched 8 neighbours
// deep (16 independent 16B loads in flight) to break the latency chain.
// ---------------------------------------------------------------------------
__global__ __launch_bounds__(256) void attn_kernel(const u16* __restrict__ qkvh,
                                                   const int* __restrict__ structure,
                                                   u16* __restrict__ attb) {
    const int head = blockIdx.x & 7, chunk = blockIdx.x >> 3;
    const int w = threadIdx.x >> 6, l = threadIdx.x & 63;
    const int ni = l >> 3, lh = l & 7;
    const int n = chunk * 32 + w * 8 + ni;

    const _Float16* qtab = (const _Float16*)qkvh;
    const _Float16* qrow = qtab + ((size_t)head * 8192 + n) * 128 + lh * 16;
    h8v q0 = *(const h8v*)qrow;
    h8v q1 = *(const h8v*)(qrow + 8);

    const int2 idx2 = ((const int2*)structure)[n * 8 + lh];   // 2 neighbour idx per lane
    const _Float16* kbase = qtab + (size_t)(8 + head) * 8192 * 128;
    const _Float16* vbase = qtab + (size_t)(16 + head) * 8192 * 128;

    float logit[16];
#pragma unroll
    for (int half = 0; half < 2; half++) {
        h8v kd0[8], kd1[8];
#pragma unroll
        for (int j8 = 0; j8 < 8; j8++) {
            const int j = half * 8 + j8;
            int idx = __shfl(j & 1 ? idx2.y : idx2.x, (ni << 3) | (j >> 1));
            const _Float16* krow = kbase + (size_t)idx * 128 + lh * 16;
            kd0[j8] = *(const h8v*)krow;
            kd1[j8] = *(const h8v*)(krow + 8);
        }
#pragma unroll
        for (int j8 = 0; j8 < 8; j8++) {
            h8v a = kd0[j8] * q0 + kd1[j8] * q1;   // per-element products (pk_fma)
            h4v a4 = a.lo + a.hi;
            h2v a2 = a4.lo + a4.hi;
            float s = (float)a2.x + (float)a2.y;
            s += __shfl_xor(s, 1);
            s += __shfl_xor(s, 2);
            s += __shfl_xor(s, 4);
            logit[half * 8 + j8] = s * SCALE;
        }
    }

    float m = logit[0];
#pragma unroll
    for (int j = 1; j < 16; j++) m = fmaxf(m, logit[j]);
    float sum = 0.f;
#pragma unroll
    for (int j = 0; j < 16; j++) { logit[j] = __expf(logit[j] - m); sum += logit[j]; }
    const float inv = 1.f / sum;

    h8v acc0 = (h8v)((_Float16)0.f);
    h8v acc1 = (h8v)((_Float16)0.f);
#pragma unroll
    for (int half = 0; half < 2; half++) {
        h8v vd0[8], vd1[8];
#pragma unroll
        for (int j8 = 0; j8 < 8; j8++) {
            const int j = half * 8 + j8;
            int idx = __shfl(j & 1 ? idx2.y : idx2.x, (ni << 3) | (j >> 1));
            const _Float16* vrow = vbase + (size_t)idx * 128 + lh * 16;
            vd0[j8] = *(const h8v*)vrow;
            vd1[j8] = *(const h8v*)(vrow + 8);
        }
#pragma unroll
        for (int j8 = 0; j8 < 8; j8++) {
            const _Float16 p = (_Float16)(logit[half * 8 + j8] * inv);
            acc0 += vd0[j8] * p;
            acc1 += vd1[j8] * p;
        }
    }

    s16x8 o0, o1;
#pragma unroll
    for (int t = 0; t < 8; t++) {
        o0[t] = (short)f2bf((float)acc0[t]);
        o1[t] = (short)f2bf((float)acc1[t]);
    }
    u16* orow = attb + (size_t)n * 1024 + head * 128 + lh * 16;   // node-major for Wo GEMM
    *(s16x8*)orow = o0;
    *(s16x8*)(orow + 8) = o1;
}

// ---------------------------------------------------------------------------
// Kernel 3: out = dist + att@Wo + bo ; then the full 4-layer MLP; out + mlp.
// Block = 2 waves sharing 16 rows, splitting the 128 columns (64 each).
// Double-buffered LDS activation tile, 1 barrier per layer.
// ---------------------------------------------------------------------------
__global__ __launch_bounds__(128) void out_mlp(const u16* __restrict__ attb,
                                               const u16* __restrict__ Wot,
                                               const u16* __restrict__ Wmlpt,
                                               const float* __restrict__ dist,
                                               const float* __restrict__ bo,
                                               const float* __restrict__ b1,
                                               const float* __restrict__ b2,
                                               const float* __restrict__ b3,
                                               const float* __restrict__ b4,
                                               float* __restrict__ out) {
    __shared__ __attribute__((aligned(16))) u16 act[2][16][136];  // [buf][row][col] padded
    const int w = threadIdx.x >> 6, l = threadIdx.x & 63;
    const int rbase = blockIdx.x * 16;
    const int cb = w * 64;                       // wave's column half

    // ---- phase A: att @ Wo  (K=1024), wave covers cols [cb, cb+64) ----
    f32x4 acc[4];
#pragma unroll
    for (int i = 0; i < 4; i++) acc[i] = (f32x4){0.f, 0.f, 0.f, 0.f};

    const u16* ap = attb + (size_t)(rbase + (l & 15)) * 1024 + ((l >> 4) * 8);
#pragma unroll 8
    for (int kk = 0; kk < 32; kk++) {
        s16x8 af = *(const s16x8*)(ap + kk * 32);
#pragma unroll
        for (int nf = 0; nf < 4; nf++) {
            const u16* bp = Wot + (size_t)(cb + nf * 16 + (l & 15)) * 1024 + kk * 32 + ((l >> 4) * 8);
            s16x8 bf = *(const s16x8*)bp;
            acc[nf] = __builtin_amdgcn_mfma_f32_16x16x32_bf16(af, bf, acc[nf], 0, 0, 0);
        }
    }

    // out = acc + bo + dist; f32 copy in regs for final residual, bf16 in LDS.
    float outsave[4][4];
#pragma unroll
    for (int nf = 0; nf < 4; nf++) {
        const int gcol = cb + nf * 16 + (l & 15);
        const float bv = bo[gcol];
#pragma unroll
        for (int r = 0; r < 4; r++) {
            const int rl = (l >> 4) * 4 + r;
            float v = acc[nf][r] + bv + dist[(size_t)(rbase + rl) * 128 + gcol];
            outsave[nf][r] = v;
            act[0][rl][gcol] = f2bf(v);
        }
    }
    __syncthreads();

    // ---- MLP chain: layer L reads buf L&1, writes buf (L+1)&1 ----
#pragma unroll
    for (int layer = 0; layer < 4; layer++) {
        const int rd = layer & 1, wr = (layer + 1) & 1;
        f32x4 macc[4];
#pragma unroll
        for (int i = 0; i < 4; i++) macc[i] = (f32x4){0.f, 0.f, 0.f, 0.f};
#pragma unroll
        for (int kk = 0; kk < 4; kk++) {
            s16x8 af = *(const s16x8*)&act[rd][l & 15][kk * 32 + ((l >> 4) * 8)];
#pragma unroll
            for (int nf = 0; nf < 4; nf++) {
                const u16* bp = Wmlpt + layer * 16384
                              + (size_t)(cb + nf * 16 + (l & 15)) * 128 + kk * 32 + ((l >> 4) * 8);
                s16x8 bf = *(const s16x8*)bp;
                macc[nf] = __builtin_amdgcn_mfma_f32_16x16x32_bf16(af, bf, macc[nf], 0, 0, 0);
            }
        }
        const float* bias = (layer == 0) ? b1 : (layer == 1) ? b2 : (layer == 2) ? b3 : b4;
        if (layer < 3) {
#pragma unroll
            for (int nf = 0; nf < 4; nf++) {
                const int gcol = cb + nf * 16 + (l & 15);
                const float bv = bias[gcol];
#pragma unroll
                for (int r = 0; r < 4; r++) {
                    const int rl = (l >> 4) * 4 + r;
                    act[wr][rl][gcol] = f2bf(fmaxf(macc[nf][r] + bv, 0.f));
                }
            }
            __syncthreads();
        } else {
#pragma unroll
            for (int nf = 0; nf < 4; nf++) {
                const int gcol = cb + nf * 16 + (l & 15);
                const float bv = bias[gcol];
#pragma unroll
                for (int r = 0; r < 4; r++) {
                    const int rl = (l >> 4) * 4 + r;
                    out[(size_t)(rbase + rl) * 128 + gcol] = outsave[nf][r] + macc[nf][r] + bv;
                }
            }
        }
    }
}

// ---------------------------------------------------------------------------
extern "C" void kernel_launch(void* const* d_in, const int* in_sizes, int n_in,
                              void* d_out, int out_size, void* d_ws, size_t ws_size,
                              hipStream_t stream) {
    const float* features = (const float*)d_in[0];
    const float* dist     = (const float*)d_in[1];
    const int*   structure= (const int*)d_in[2];
    const float* Wq = (const float*)d_in[3];  const float* bq = (const float*)d_in[4];
    const float* Wk = (const float*)d_in[5];  const float* bk = (const float*)d_in[6];
    const float* Wv = (const float*)d_in[7];  const float* bv = (const float*)d_in[8];
    const float* Wo = (const float*)d_in[9];  const float* bo = (const float*)d_in[10];
    const float* W1 = (const float*)d_in[11]; const float* b1 = (const float*)d_in[12];
    const float* W2 = (const float*)d_in[13]; const float* b2 = (const float*)d_in[14];
    const float* W3 = (const float*)d_in[15]; const float* b3 = (const float*)d_in[16];
    const float* W4 = (const float*)d_in[17]; const float* b4 = (const float*)d_in[18];
    float* out = (float*)d_out;

    u16* wsp   = (u16*)d_ws;
    u16* qkvh  = wsp;                                   // [3][8][8192][128] f16 head-major
    u16* attb  = qkvh  + (size_t)3 * 8 * 8192 * 128;    // [8192][1024] bf16
    u16* featb = attb  + (size_t)8192 * 1024;           // [8192][128] bf16
    u16* distb = featb + (size_t)8192 * 128;            // [8192][128] bf16
    u16* Wqkvt = distb + (size_t)8192 * 128;            // [3072][128] bf16
    u16* Wot   = Wqkvt + (size_t)3072 * 128;            // [128][1024] bf16
    u16* Wmlpt = Wot   + (size_t)128 * 1024;            // [4][128][128] bf16
    float* bqkv = (float*)(Wmlpt + (size_t)4 * 128 * 128); // [3072]

    prep_kernel<<<4096, 256, 0, stream>>>(features, dist, Wq, Wk, Wv, Wo, W1, W2, W3, W4,
                                          bq, bk, bv, featb, distb, Wqkvt, Wot, Wmlpt, bqkv);
    qkv_gemm<<<dim3(32, 24), 256, 0, stream>>>(featb, distb, Wqkvt, bqkv, qkvh);
    attn_kernel<<<2048, 256, 0, stream>>>(qkvh, structure, attb);
    out_mlp<<<512, 128, 0, stream>>>(attb, Wot, Wmlpt, dist, bo, b1, b2, b3, b4, out);
}

// Round 16
// 188.283 us; speedup vs baseline: 1.3488x; 1.0059x over previous
//
#include <hip/hip_runtime.h>
#include <hip/hip_bf16.h>

typedef float f32x4 __attribute__((ext_vector_type(4)));
typedef short s16x8 __attribute__((ext_vector_type(8)));
typedef _Float16 h8v __attribute__((ext_vector_type(8)));
typedef _Float16 h4v __attribute__((ext_vector_type(4)));
typedef _Float16 h2v __attribute__((ext_vector_type(2)));
typedef unsigned short u16;

#define N_NODES 8192
#define KNBR 16
#define SCALE 0.08838834764831845f   // 1/sqrt(128)

__device__ __forceinline__ float bf2f(u16 h) {
    unsigned v = ((unsigned)h) << 16;
    return __builtin_bit_cast(float, v);
}
__device__ __forceinline__ u16 f2bf(float f) {
    __hip_bfloat16 h = __float2bfloat16(f);   // RNE; compiler emits cvt_pk pairs
    return __builtin_bit_cast(u16, h);
}
__device__ __forceinline__ u16 f2h(float f) {
    _Float16 h = (_Float16)f;                  // RNE f32->f16
    return __builtin_bit_cast(u16, h);
}

// ---------------------------------------------------------------------------
// Kernel 0: activations -> bf16; weights transposed+converted so B-fragments
// (Wt[col][k]) are contiguous 16B reads; fused qkv bias table.
// ---------------------------------------------------------------------------
__global__ void prep_kernel(const float* __restrict__ feat, const float* __restrict__ dist,
                            const float* __restrict__ Wq, const float* __restrict__ Wk,
                            const float* __restrict__ Wv, const float* __restrict__ Wo,
                            const float* __restrict__ W1, const float* __restrict__ W2,
                            const float* __restrict__ W3, const float* __restrict__ W4,
                            const float* __restrict__ bq, const float* __restrict__ bk,
                            const float* __restrict__ bv,
                            u16* __restrict__ featb, u16* __restrict__ distb,
                            u16* __restrict__ Wqkvt, u16* __restrict__ Wot,
                            u16* __restrict__ Wmlpt, float* __restrict__ bqkv) {
    int gid = blockIdx.x * 256 + threadIdx.x;       // grid covers exactly 8192*128
    featb[gid] = f2bf(feat[gid]);
    distb[gid] = f2bf(dist[gid]);
    if (gid < 3072 * 128) {                         // Wqkvt[col][k], col: q|k|v
        int col = gid >> 7, k = gid & 127;
        float v = (col < 1024) ? Wq[k * 1024 + col]
                : (col < 2048) ? Wk[k * 1024 + (col - 1024)]
                               : Wv[k * 1024 + (col - 2048)];
        Wqkvt[gid] = f2bf(v);
    }
    if (gid < 128 * 1024) {                         // Wot[col][k], k=0..1023
        int col = gid >> 10, k = gid & 1023;
        Wot[gid] = f2bf(Wo[k * 128 + col]);
    }
    if (gid < 4 * 128 * 128) {                      // Wmlpt[layer][col][k]
        int m = gid >> 14, r = gid & 16383;
        int col = r >> 7, k = r & 127;
        const float* Wm = (m == 0) ? W1 : (m == 1) ? W2 : (m == 2) ? W3 : W4;
        Wmlpt[gid] = f2bf(Wm[k * 128 + col]);
    }
    if (gid < 3072) {
        bqkv[gid] = (gid < 1024) ? bq[gid] : (gid < 2048) ? bk[gid - 1024] : bv[gid - 2048];
    }
}

// ---------------------------------------------------------------------------
// Kernel 1: fused Q/K/V projection GEMM.  M=8192, K=128, N=3072 (q|k|v).
// Block = 4 waves; each wave owns a 64x128 output tile.  128 MFMA : 48 loads.
// Output is written HEAD-MAJOR as **f16** (qkvh[s][h][n][d]) for the packed-
// f16 attention gather; attb (attn output) stays bf16 for the Wo MFMA.
// ---------------------------------------------------------------------------
__global__ __launch_bounds__(256, 2) void qkv_gemm(const u16* __restrict__ featb,
                                                   const u16* __restrict__ distb,
                                                   const u16* __restrict__ Wqkvt,
                                                   const float* __restrict__ bqkv,
                                                   u16* __restrict__ qkvh) {
    const int rt = blockIdx.x, ct = blockIdx.y;      // 32 x 24
    const int w = threadIdx.x >> 6, l = threadIdx.x & 63;
    const int rbase = rt * 256 + w * 64;
    const int cbase = ct * 128;
    const u16* A = (ct < 8) ? distb : featb;         // q from distance feats

    // preload A fragments: mf 0..3 (16-row groups), kk 0..3 (32-k slices)
    s16x8 af[4][4];
#pragma unroll
    for (int mf = 0; mf < 4; mf++) {
        const u16* ar = A + (size_t)(rbase + mf * 16 + (l & 15)) * 128 + ((l >> 4) * 8);
#pragma unroll
        for (int kk = 0; kk < 4; kk++) af[mf][kk] = *(const s16x8*)(ar + kk * 32);
    }

    f32x4 acc[4][8];
#pragma unroll
    for (int mf = 0; mf < 4; mf++)
#pragma unroll
        for (int nf = 0; nf < 8; nf++) acc[mf][nf] = (f32x4){0.f, 0.f, 0.f, 0.f};

#pragma unroll
    for (int nf = 0; nf < 8; nf++) {
        const u16* bp = Wqkvt + (size_t)(cbase + nf * 16 + (l & 15)) * 128 + ((l >> 4) * 8);
        s16x8 b0 = *(const s16x8*)bp;
        s16x8 b1 = *(const s16x8*)(bp + 32);
        s16x8 b2 = *(const s16x8*)(bp + 64);
        s16x8 b3 = *(const s16x8*)(bp + 96);
#pragma unroll
        for (int mf = 0; mf < 4; mf++) {
            acc[mf][nf] = __builtin_amdgcn_mfma_f32_16x16x32_bf16(af[mf][0], b0, acc[mf][nf], 0, 0, 0);
            acc[mf][nf] = __builtin_amdgcn_mfma_f32_16x16x32_bf16(af[mf][1], b1, acc[mf][nf], 0, 0, 0);
            acc[mf][nf] = __builtin_amdgcn_mfma_f32_16x16x32_bf16(af[mf][2], b2, acc[mf][nf], 0, 0, 0);
            acc[mf][nf] = __builtin_amdgcn_mfma_f32_16x16x32_bf16(af[mf][3], b3, acc[mf][nf], 0, 0, 0);
        }
    }

    float bias[8];
#pragma unroll
    for (int nf = 0; nf < 8; nf++) bias[nf] = bqkv[cbase + nf * 16 + (l & 15)];

    u16* obase = qkvh + ((size_t)ct * 8192 + rbase) * 128 + (l & 15);
#pragma unroll
    for (int mf = 0; mf < 4; mf++) {
#pragma unroll
        for (int nf = 0; nf < 8; nf++) {
#pragma unroll
            for (int r = 0; r < 4; r++) {
                const int row = mf * 16 + (l >> 4) * 4 + r;
                obase[(size_t)row * 128 + nf * 16] = f2h(acc[mf][nf][r] + bias[nf]);
            }
        }
    }
}

// ---------------------------------------------------------------------------
// Kernel 2: gather attention, head-partitioned (head = blockIdx.x & 7 -> one
// XCD; per-XCD K/V working set = 4MB = L2).  Packed-f16 math; loads batched
// 8 neighbours deep.
// ---------------------------------------------------------------------------
__global__ __launch_bounds__(256) void attn_kernel(const u16* __restrict__ qkvh,
                                                   const int* __restrict__ structure,
                                                   u16* __restrict__ attb) {
    const int head = blockIdx.x & 7, chunk = blockIdx.x >> 3;
    const int w = threadIdx.x >> 6, l = threadIdx.x & 63;
    const int ni = l >> 3, lh = l & 7;
    const int n = chunk * 32 + w * 8 + ni;

    const _Float16* qtab = (const _Float16*)qkvh;
    const _Float16* qrow = qtab + ((size_t)head * 8192 + n) * 128 + lh * 16;
    h8v q0 = *(const h8v*)qrow;
    h8v q1 = *(const h8v*)(qrow + 8);

    const int2 idx2 = ((const int2*)structure)[n * 8 + lh];   // 2 neighbour idx per lane
    const _Float16* kbase = qtab + (size_t)(8 + head) * 8192 * 128;
    const _Float16* vbase = qtab + (size_t)(16 + head) * 8192 * 128;

    float logit[16];
#pragma unroll
    for (int half = 0; half < 2; half++) {
        h8v kd0[8], kd1[8];
#pragma unroll
        for (int j8 = 0; j8 < 8; j8++) {
            const int j = half * 8 + j8;
            int idx = __shfl(j & 1 ? idx2.y : idx2.x, (ni << 3) | (j >> 1));
            const _Float16* krow = kbase + (size_t)idx * 128 + lh * 16;
            kd0[j8] = *(const h8v*)krow;
            kd1[j8] = *(const h8v*)(krow + 8);
        }
#pragma unroll
        for (int j8 = 0; j8 < 8; j8++) {
            h8v a = kd0[j8] * q0 + kd1[j8] * q1;   // per-element products (pk_fma)
            h4v a4 = a.lo + a.hi;
            h2v a2 = a4.lo + a4.hi;
            float s = (float)a2.x + (float)a2.y;
            s += __shfl_xor(s, 1);
            s += __shfl_xor(s, 2);
            s += __shfl_xor(s, 4);
            logit[half * 8 + j8] = s * SCALE;
        }
    }

    float m = logit[0];
#pragma unroll
    for (int j = 1; j < 16; j++) m = fmaxf(m, logit[j]);
    float sum = 0.f;
#pragma unroll
    for (int j = 0; j < 16; j++) { logit[j] = __expf(logit[j] - m); sum += logit[j]; }
    const float inv = 1.f / sum;

    h8v acc0 = (h8v)((_Float16)0.f);
    h8v acc1 = (h8v)((_Float16)0.f);
#pragma unroll
    for (int half = 0; half < 2; half++) {
        h8v vd0[8], vd1[8];
#pragma unroll
        for (int j8 = 0; j8 < 8; j8++) {
            const int j = half * 8 + j8;
            int idx = __shfl(j & 1 ? idx2.y : idx2.x, (ni << 3) | (j >> 1));
            const _Float16* vrow = vbase + (size_t)idx * 128 + lh * 16;
            vd0[j8] = *(const h8v*)vrow;
            vd1[j8] = *(const h8v*)(vrow + 8);
        }
#pragma unroll
        for (int j8 = 0; j8 < 8; j8++) {
            const _Float16 p = (_Float16)(logit[half * 8 + j8] * inv);
            acc0 += vd0[j8] * p;
            acc1 += vd1[j8] * p;
        }
    }

    s16x8 o0, o1;
#pragma unroll
    for (int t = 0; t < 8; t++) {
        o0[t] = (short)f2bf((float)acc0[t]);
        o1[t] = (short)f2bf((float)acc1[t]);
    }
    u16* orow = attb + (size_t)n * 1024 + head * 128 + lh * 16;   // node-major for Wo GEMM
    *(s16x8*)orow = o0;
    *(s16x8*)(orow + 8) = o1;
}

// ---------------------------------------------------------------------------
// Kernel 3: out = dist + att@Wo + bo ; then the full 4-layer MLP; out + mlp.
// OCCUPANCY REWORK: 512 blocks x 4 waves (was x2) -> 2048 waves = 2/SIMD.
// Phase A: K-SPLIT x4 — wave w computes the partial Wo-GEMM over
// k in [w*256,(w+1)*256) for all 128 cols x 16 rows (64 MFMA, 8-deep
// B-load batches), partials reduced through LDS f32.
// MLP: col-split x4 (wave w owns cols [w*32,(w+1)*32), 8 MFMA/layer).
// LDS: part 32KB + outf 8KB + act 8.7KB = 49.7KB -> 3 blocks/CU.
// ---------------------------------------------------------------------------
__global__ __launch_bounds__(256) void out_mlp(const u16* __restrict__ attb,
                                               const u16* __restrict__ Wot,
                                               const u16* __restrict__ Wmlpt,
                                               const float* __restrict__ dist,
                                               const float* __restrict__ bo,
                                               const float* __restrict__ b1,
                                               const float* __restrict__ b2,
                                               const float* __restrict__ b3,
                                               const float* __restrict__ b4,
                                               float* __restrict__ out) {
    __shared__ __attribute__((aligned(16))) float part[4][16][128];  // 32KB
    __shared__ __attribute__((aligned(16))) float outf[16][128];     // 8KB
    __shared__ __attribute__((aligned(16))) u16 act[2][16][136];     // 8.7KB padded
    const int w = threadIdx.x >> 6, l = threadIdx.x & 63;
    const int rbase = blockIdx.x * 16;

    // ---- phase A: partial att @ Wo over K-quarter [w*256, w*256+256) ----
    f32x4 acc[8];
#pragma unroll
    for (int i = 0; i < 8; i++) acc[i] = (f32x4){0.f, 0.f, 0.f, 0.f};

    const u16* ap = attb + (size_t)(rbase + (l & 15)) * 1024 + w * 256 + ((l >> 4) * 8);
    s16x8 af[8];
#pragma unroll
    for (int kk = 0; kk < 8; kk++) af[kk] = *(const s16x8*)(ap + kk * 32);

#pragma unroll
    for (int nf = 0; nf < 8; nf++) {
        const u16* bp = Wot + (size_t)(nf * 16 + (l & 15)) * 1024 + w * 256 + ((l >> 4) * 8);
        s16x8 bf[8];
#pragma unroll
        for (int kk = 0; kk < 8; kk++) bf[kk] = *(const s16x8*)(bp + kk * 32);
#pragma unroll
        for (int kk = 0; kk < 8; kk++)
            acc[nf] = __builtin_amdgcn_mfma_f32_16x16x32_bf16(af[kk], bf[kk], acc[nf], 0, 0, 0);
    }

    // write partials to LDS
#pragma unroll
    for (int nf = 0; nf < 8; nf++) {
        const int gcol = nf * 16 + (l & 15);
#pragma unroll
        for (int r = 0; r < 4; r++) {
            part[w][(l >> 4) * 4 + r][gcol] = acc[nf][r];
        }
    }
    __syncthreads();

    // ---- reduce 4 partials + bias + dist residual; thread strip of 8 ----
    {
        const int tid = threadIdx.x;
        const int row = tid >> 4, col0 = (tid & 15) * 8;
        f32x4 s0 = *(const f32x4*)&part[0][row][col0];
        f32x4 s1 = *(const f32x4*)&part[0][row][col0 + 4];
#pragma unroll
        for (int ww = 1; ww < 4; ww++) {
            s0 += *(const f32x4*)&part[ww][row][col0];
            s1 += *(const f32x4*)&part[ww][row][col0 + 4];
        }
        const float* dp = dist + (size_t)(rbase + row) * 128 + col0;
        f32x4 d0 = *(const f32x4*)dp;
        f32x4 d1 = *(const f32x4*)(dp + 4);
        f32x4 bo0 = *(const f32x4*)(bo + col0);
        f32x4 bo1 = *(const f32x4*)(bo + col0 + 4);
        s0 += d0 + bo0;
        s1 += d1 + bo1;
        *(f32x4*)&outf[row][col0] = s0;
        *(f32x4*)&outf[row][col0 + 4] = s1;
#pragma unroll
        for (int e = 0; e < 4; e++) {
            act[0][row][col0 + e] = f2bf(s0[e]);
            act[0][row][col0 + 4 + e] = f2bf(s1[e]);
        }
    }
    __syncthreads();

    // ---- MLP chain: wave w owns cols [w*32, w*32+32); layer L: buf L&1 -> (L+1)&1
    const int cw = w * 32;
#pragma unroll
    for (int layer = 0; layer < 4; layer++) {
        const int rd = layer & 1, wr = (layer + 1) & 1;
        f32x4 macc[2];
        macc[0] = (f32x4){0.f, 0.f, 0.f, 0.f};
        macc[1] = (f32x4){0.f, 0.f, 0.f, 0.f};
#pragma unroll
        for (int kk = 0; kk < 4; kk++) {
            s16x8 af2 = *(const s16x8*)&act[rd][l & 15][kk * 32 + ((l >> 4) * 8)];
#pragma unroll
            for (int nf = 0; nf < 2; nf++) {
                const u16* bp = Wmlpt + layer * 16384
                              + (size_t)(cw + nf * 16 + (l & 15)) * 128 + kk * 32 + ((l >> 4) * 8);
                s16x8 bf = *(const s16x8*)bp;
                macc[nf] = __builtin_amdgcn_mfma_f32_16x16x32_bf16(af2, bf, macc[nf], 0, 0, 0);
            }
        }
        const float* bias = (layer == 0) ? b1 : (layer == 1) ? b2 : (layer == 2) ? b3 : b4;
        if (layer < 3) {
#pragma unroll
            for (int nf = 0; nf < 2; nf++) {
                const int gcol = cw + nf * 16 + (l & 15);
                const float bv = bias[gcol];
#pragma unroll
                for (int r = 0; r < 4; r++) {
                    const int rl = (l >> 4) * 4 + r;
                    act[wr][rl][gcol] = f2bf(fmaxf(macc[nf][r] + bv, 0.f));
                }
            }
            __syncthreads();
        } else {
#pragma unroll
            for (int nf = 0; nf < 2; nf++) {
                const int gcol = cw + nf * 16 + (l & 15);
                const float bv = bias[gcol];
#pragma unroll
                for (int r = 0; r < 4; r++) {
                    const int rl = (l >> 4) * 4 + r;
                    out[(size_t)(rbase + rl) * 128 + gcol] = outf[rl][gcol] + macc[nf][r] + bv;
                }
            }
        }
    }
}

// ---------------------------------------------------------------------------
extern "C" void kernel_launch(void* const* d_in, const int* in_sizes, int n_in,
                              void* d_out, int out_size, void* d_ws, size_t ws_size,
                              hipStream_t stream) {
    const float* features = (const float*)d_in[0];
    const float* dist     = (const float*)d_in[1];
    const int*   structure= (const int*)d_in[2];
    const float* Wq = (const float*)d_in[3];  const float* bq = (const float*)d_in[4];
    const float* Wk = (const float*)d_in[5];  const float* bk = (const float*)d_in[6];
    const float* Wv = (const float*)d_in[7];  const float* bv = (const float*)d_in[8];
    const float* Wo = (const float*)d_in[9];  const float* bo = (const float*)d_in[10];
    const float* W1 = (const float*)d_in[11]; const float* b1 = (const float*)d_in[12];
    const float* W2 = (const float*)d_in[13]; const float* b2 = (const float*)d_in[14];
    const float* W3 = (const float*)d_in[15]; const float* b3 = (const float*)d_in[16];
    const float* W4 = (const float*)d_in[17]; const float* b4 = (const float*)d_in[18];
    float* out = (float*)d_out;

    u16* wsp   = (u16*)d_ws;
    u16* qkvh  = wsp;                                   // [3][8][8192][128] f16 head-major
    u16* attb  = qkvh  + (size_t)3 * 8 * 8192 * 128;    // [8192][1024] bf16
    u16* featb = attb  + (size_t)8192 * 1024;           // [8192][128] bf16
    u16* distb = featb + (size_t)8192 * 128;            // [8192][128] bf16
    u16* Wqkvt = distb + (size_t)8192 * 128;            // [3072][128] bf16
    u16* Wot   = Wqkvt + (size_t)3072 * 128;            // [128][1024] bf16
    u16* Wmlpt = Wot   + (size_t)128 * 1024;            // [4][128][128] bf16
    float* bqkv = (float*)(Wmlpt + (size_t)4 * 128 * 128); // [3072]

    prep_kernel<<<4096, 256, 0, stream>>>(features, dist, Wq, Wk, Wv, Wo, W1, W2, W3, W4,
                                          bq, bk, bv, featb, distb, Wqkvt, Wot, Wmlpt, bqkv);
    qkv_gemm<<<dim3(32, 24), 256, 0, stream>>>(featb, distb, Wqkvt, bqkv, qkvh);
    attn_kernel<<<2048, 256, 0, stream>>>(qkvh, structure, attb);
    out_mlp<<<512, 256, 0, stream>>>(attb, Wot, Wmlpt, dist, bo, b1, b2, b3, b4, out);
}